// Round 1
// baseline (9681.978 us; speedup 1.0000x reference)
//
#include <hip/hip_runtime.h>
#include <hip/hip_bf16.h>

// Problem constants (from reference)
#define N_NODES 100000
#define N_EDGES 1600000
#define HID 128
#define OUTC 64
#define NLAYERS 3

// ---------------------------------------------------------------------------
// GEMM: Y[n][c] = sum_k X[n][k] * W[k][COLS+c] (+bias). K fixed at 128.
// Block = 256 threads covering 16 rows. Each wave handles 4 consecutive rows
// (uniform row per lane-group -> x loads are broadcast, L1-resident).
// NC = columns per thread (2 for COLS=128, 1 for COLS=64).
// ---------------------------------------------------------------------------
template <int NC>
__global__ __launch_bounds__(256) void gemm_kernel(
    const float* __restrict__ X, const float* __restrict__ W,
    const float* __restrict__ bias, float* __restrict__ Y) {
  const int COLS = NC * 64;
  const int c0 = threadIdx.x & 63;
  const int rg = threadIdx.x >> 6;           // 0..3 (wave id)
  const int row0 = blockIdx.x * 16 + rg * 4; // 4 consecutive rows per thread

  float acc[4][NC];
#pragma unroll
  for (int r = 0; r < 4; ++r)
#pragma unroll
    for (int j = 0; j < NC; ++j) acc[r][j] = 0.f;

  const float* x0 = X + (size_t)row0 * 128;

  for (int k4 = 0; k4 < 32; ++k4) {
    float4 xv[4];
#pragma unroll
    for (int r = 0; r < 4; ++r)
      xv[r] = *reinterpret_cast<const float4*>(x0 + r * 128 + k4 * 4);
#pragma unroll
    for (int kk = 0; kk < 4; ++kk) {
#pragma unroll
      for (int j = 0; j < NC; ++j) {
        const float w = W[(k4 * 4 + kk) * COLS + c0 + j * 64];
#pragma unroll
        for (int r = 0; r < 4; ++r)
          acc[r][j] += reinterpret_cast<const float*>(&xv[r])[kk] * w;
      }
    }
  }

#pragma unroll
  for (int r = 0; r < 4; ++r)
#pragma unroll
    for (int j = 0; j < NC; ++j) {
      const int c = c0 + j * 64;
      float v = acc[r][j];
      if (bias) v += bias[c];
      Y[(size_t)(row0 + r) * COLS + c] = v;
    }
}

// ---------------------------------------------------------------------------
// Scatter: agg[col[e]][:] += h[row[e]][:].  32 lanes per edge, float4 each.
// ---------------------------------------------------------------------------
__global__ __launch_bounds__(256) void scatter_kernel(
    const float* __restrict__ h, const int* __restrict__ row,
    const int* __restrict__ col, float* __restrict__ agg) {
  const int g = blockIdx.x * 256 + threadIdx.x;
  const int e = g >> 5;
  if (e >= N_EDGES) return;
  const int l = g & 31;
  const int r = row[e];
  const int c = col[e];
  const int ch = l * 4;
  const float4 v = *reinterpret_cast<const float4*>(h + (size_t)r * 128 + ch);
  float* dst = agg + (size_t)c * 128 + ch;
  atomicAdd(dst + 0, v.x);
  atomicAdd(dst + 1, v.y);
  atomicAdd(dst + 2, v.z);
  atomicAdd(dst + 3, v.w);
}

// ---------------------------------------------------------------------------
// Degree: deg[row[e]] += 1  (edge structure only; computed once per call)
// ---------------------------------------------------------------------------
__global__ __launch_bounds__(256) void deg_kernel(const int* __restrict__ row,
                                                  float* __restrict__ deg) {
  const int e = blockIdx.x * 256 + threadIdx.x;
  if (e >= N_EDGES) return;
  atomicAdd(deg + row[e], 1.0f);
}

// ---------------------------------------------------------------------------
// ReLU + bias (in place): agg = relu(agg + b)   -> becomes x_new
// ---------------------------------------------------------------------------
__global__ __launch_bounds__(256) void relu_bias_kernel(
    float* __restrict__ agg, const float* __restrict__ b) {
  const size_t i4 = (size_t)blockIdx.x * 256 + threadIdx.x; // float4 index
  if (i4 >= (size_t)N_NODES * 32) return;
  const int c4 = (int)(i4 & 31) * 4;
  float4 v = reinterpret_cast<float4*>(agg)[i4];
  const float4 bb = *reinterpret_cast<const float4*>(b + c4);
  v.x = fmaxf(v.x + bb.x, 0.f);
  v.y = fmaxf(v.y + bb.y, 0.f);
  v.z = fmaxf(v.z + bb.z, 0.f);
  v.w = fmaxf(v.w + bb.w, 0.f);
  reinterpret_cast<float4*>(agg)[i4] = v;
}

// ---------------------------------------------------------------------------
// Tau edge pass: tau_vals[row[e]] += ||x_new[row[e]] - x_new[col[e]]||^2
// 32 lanes per edge, float4 each, half-wave shuffle reduce, 1 atomic/edge.
// ---------------------------------------------------------------------------
__global__ __launch_bounds__(256) void tau_edge_kernel(
    const float* __restrict__ xn, const int* __restrict__ row,
    const int* __restrict__ col, float* __restrict__ tau_vals) {
  const int g = blockIdx.x * 256 + threadIdx.x;
  const int e = g >> 5;
  if (e >= N_EDGES) return;
  const int l = g & 31;
  const int r = row[e];
  const int c = col[e];
  const int ch = l * 4;
  const float4 a = *reinterpret_cast<const float4*>(xn + (size_t)r * 128 + ch);
  const float4 b = *reinterpret_cast<const float4*>(xn + (size_t)c * 128 + ch);
  const float d0 = a.x - b.x, d1 = a.y - b.y, d2 = a.z - b.z, d3 = a.w - b.w;
  float s = d0 * d0 + d1 * d1 + d2 * d2 + d3 * d3;
  // reduce within the 32-lane group (xor offsets < 32 stay inside the half)
  s += __shfl_xor(s, 16);
  s += __shfl_xor(s, 8);
  s += __shfl_xor(s, 4);
  s += __shfl_xor(s, 2);
  s += __shfl_xor(s, 1);
  if ((threadIdx.x & 31) == 0) atomicAdd(tau_vals + r, s);
}

// ---------------------------------------------------------------------------
// Tau finalize: tau[n] = tanh(tau_vals[n] / (deg[n] + 1e-10))
// ---------------------------------------------------------------------------
__global__ __launch_bounds__(256) void tau_fin_kernel(
    const float* __restrict__ tau_vals, const float* __restrict__ deg,
    float* __restrict__ tau) {
  const int n = blockIdx.x * 256 + threadIdx.x;
  if (n >= N_NODES) return;
  tau[n] = tanhf(tau_vals[n] / (deg[n] + 1e-10f));
}

// ---------------------------------------------------------------------------
// Gated update: x = (1-tau)*x + tau*x_new   (tau per node)
// ---------------------------------------------------------------------------
__global__ __launch_bounds__(256) void update_kernel(
    float* __restrict__ x, const float* __restrict__ xn,
    const float* __restrict__ tau) {
  const size_t i4 = (size_t)blockIdx.x * 256 + threadIdx.x; // float4 index
  if (i4 >= (size_t)N_NODES * 32) return;
  const int n = (int)(i4 >> 5);
  const float t = tau[n];
  float4 xv = reinterpret_cast<float4*>(x)[i4];
  const float4 nv = reinterpret_cast<const float4*>(xn)[i4];
  xv.x = (1.f - t) * xv.x + t * nv.x;
  xv.y = (1.f - t) * xv.y + t * nv.y;
  xv.z = (1.f - t) * xv.z + t * nv.z;
  xv.w = (1.f - t) * xv.w + t * nv.w;
  reinterpret_cast<float4*>(x)[i4] = xv;
}

// ---------------------------------------------------------------------------
extern "C" void kernel_launch(void* const* d_in, const int* in_sizes, int n_in,
                              void* d_out, int out_size, void* d_ws,
                              size_t ws_size, hipStream_t stream) {
  const float* x_in = (const float*)d_in[0];
  const int* ei = (const int*)d_in[1]; // [2][N_EDGES]; row = ei, col = ei+E
  const float* W_in = (const float*)d_in[2];
  const float* W_convs = (const float*)d_in[3]; // [3][128][128]
  const float* b_convs = (const float*)d_in[4]; // [3][128]
  const float* W_fc = (const float*)d_in[5];    // [128][64]
  const float* b_fc = (const float*)d_in[6];    // [64]
  float* out = (float*)d_out;

  const int* row = ei;
  const int* col = ei + N_EDGES;

  // Workspace layout (floats)
  const size_t NF = (size_t)N_NODES * HID; // 12.8M
  float* x_cur = (float*)d_ws;
  float* h = x_cur + NF;
  float* agg = h + NF; // becomes x_new after relu_bias
  float* tau_vals = agg + NF;
  float* deg = tau_vals + 102400;
  float* tau = deg + 102400;
  // total ~154.8 MB

  const int GEMM_BLOCKS = N_NODES / 16;              // 6250
  const int EDGE32_BLOCKS = (N_EDGES * 32) / 256;    // 200000
  const int EDGE_BLOCKS = (N_EDGES + 255) / 256;     // 6250
  const int NODE4_BLOCKS = (int)((N_NODES * 32) / 256); // 12500
  const int NODE_BLOCKS = (N_NODES + 255) / 256;     // 391

  // 1. x = x_in @ W_in
  gemm_kernel<2><<<GEMM_BLOCKS, 256, 0, stream>>>(x_in, W_in, nullptr, x_cur);

  // 2. degree (structure-only, reused across layers)
  hipMemsetAsync(deg, 0, N_NODES * sizeof(float), stream);
  deg_kernel<<<EDGE_BLOCKS, 256, 0, stream>>>(row, deg);

  for (int l = 0; l < NLAYERS; ++l) {
    const float* Wl = W_convs + (size_t)l * HID * HID;
    const float* bl = b_convs + (size_t)l * HID;

    // h = x @ W_convs[l]
    gemm_kernel<2><<<GEMM_BLOCKS, 256, 0, stream>>>(x_cur, Wl, nullptr, h);

    // agg = segment_sum(h[row], col)
    hipMemsetAsync(agg, 0, NF * sizeof(float), stream);
    scatter_kernel<<<EDGE32_BLOCKS, 256, 0, stream>>>(h, row, col, agg);

    // x_new = relu(agg + b)   (in place)
    relu_bias_kernel<<<NODE4_BLOCKS, 256, 0, stream>>>(agg, bl);

    // tau
    hipMemsetAsync(tau_vals, 0, N_NODES * sizeof(float), stream);
    tau_edge_kernel<<<EDGE32_BLOCKS, 256, 0, stream>>>(agg, row, col, tau_vals);
    tau_fin_kernel<<<NODE_BLOCKS, 256, 0, stream>>>(tau_vals, deg, tau);

    // x = (1-tau)*x + tau*x_new
    update_kernel<<<NODE4_BLOCKS, 256, 0, stream>>>(x_cur, agg, tau);
  }

  // out = x @ W_fc + b_fc
  gemm_kernel<1><<<GEMM_BLOCKS, 256, 0, stream>>>(x_cur, W_fc, b_fc, out);
}

// Round 2
// 1968.729 us; speedup vs baseline: 4.9179x; 4.9179x over previous
//
#include <hip/hip_runtime.h>
#include <hip/hip_bf16.h>

// Problem constants (from reference)
#define N_NODES 100000
#define N_EDGES 1600000
#define HID 128
#define OUTC 64
#define NLAYERS 3

#define SCAN_N (2 * N_NODES)   // joint scan over [row_counts | col_counts]
#define SCAN_B 1024
#define SCAN_NB ((SCAN_N + SCAN_B - 1) / SCAN_B)  // 196

// ---------------------------------------------------------------------------
// GEMM: Y[n][c] = sum_k X[n][k] * W[k][c] (+bias). K fixed at 128.
// Block = 256 threads covering 16 rows; wave-uniform rows -> x loads broadcast.
// ---------------------------------------------------------------------------
template <int NC>
__global__ __launch_bounds__(256) void gemm_kernel(
    const float* __restrict__ X, const float* __restrict__ W,
    const float* __restrict__ bias, float* __restrict__ Y) {
  const int COLS = NC * 64;
  const int c0 = threadIdx.x & 63;
  const int rg = threadIdx.x >> 6;
  const int row0 = blockIdx.x * 16 + rg * 4;

  float acc[4][NC];
#pragma unroll
  for (int r = 0; r < 4; ++r)
#pragma unroll
    for (int j = 0; j < NC; ++j) acc[r][j] = 0.f;

  const float* x0 = X + (size_t)row0 * 128;

  for (int k4 = 0; k4 < 32; ++k4) {
    float4 xv[4];
#pragma unroll
    for (int r = 0; r < 4; ++r)
      xv[r] = *reinterpret_cast<const float4*>(x0 + r * 128 + k4 * 4);
#pragma unroll
    for (int kk = 0; kk < 4; ++kk) {
#pragma unroll
      for (int j = 0; j < NC; ++j) {
        const float w = W[(k4 * 4 + kk) * COLS + c0 + j * 64];
#pragma unroll
        for (int r = 0; r < 4; ++r)
          acc[r][j] += reinterpret_cast<const float*>(&xv[r])[kk] * w;
      }
    }
  }

#pragma unroll
  for (int r = 0; r < 4; ++r)
#pragma unroll
    for (int j = 0; j < NC; ++j) {
      const int c = c0 + j * 64;
      float v = acc[r][j];
      if (bias) v += bias[c];
      Y[(size_t)(row0 + r) * COLS + c] = v;
    }
}

// ---------------------------------------------------------------------------
// CSR build step 1: per-node in/out degree counts.
// counts[0..N)  = out-degree (keyed by row)   -> tau segment
// counts[N..2N) = in-degree  (keyed by col)   -> aggregation segment
// ---------------------------------------------------------------------------
__global__ __launch_bounds__(256) void count_kernel(const int* __restrict__ row,
                                                    const int* __restrict__ col,
                                                    int* __restrict__ counts) {
  const int e = blockIdx.x * 256 + threadIdx.x;
  if (e >= N_EDGES) return;
  atomicAdd(counts + row[e], 1);
  atomicAdd(counts + N_NODES + col[e], 1);
}

// ---------------------------------------------------------------------------
// Scan step A: per-block inclusive scan (Hillis-Steele in LDS) + block sums.
// ---------------------------------------------------------------------------
__global__ __launch_bounds__(SCAN_B) void scan1_kernel(
    const int* __restrict__ counts, int* __restrict__ incl,
    int* __restrict__ bsum) {
  __shared__ int tmp[SCAN_B];
  const int i = blockIdx.x * SCAN_B + threadIdx.x;
  tmp[threadIdx.x] = (i < SCAN_N) ? counts[i] : 0;
  __syncthreads();
  for (int d = 1; d < SCAN_B; d <<= 1) {
    int t = (threadIdx.x >= d) ? tmp[threadIdx.x - d] : 0;
    __syncthreads();
    tmp[threadIdx.x] += t;
    __syncthreads();
  }
  if (i < SCAN_N) incl[i] = tmp[threadIdx.x];
  if (threadIdx.x == SCAN_B - 1) bsum[blockIdx.x] = tmp[SCAN_B - 1];
}

// Scan step B: single block scans the block sums (SCAN_NB <= 256).
__global__ __launch_bounds__(256) void scan2_kernel(int* __restrict__ bsum) {
  __shared__ int tmp[256];
  tmp[threadIdx.x] = (threadIdx.x < SCAN_NB) ? bsum[threadIdx.x] : 0;
  __syncthreads();
  for (int d = 1; d < 256; d <<= 1) {
    int t = (threadIdx.x >= d) ? tmp[threadIdx.x - d] : 0;
    __syncthreads();
    tmp[threadIdx.x] += t;
    __syncthreads();
  }
  if (threadIdx.x < SCAN_NB) bsum[threadIdx.x] = tmp[threadIdx.x];
}

// Scan step C: add scanned block offsets; also init cursors to exclusive start.
__global__ __launch_bounds__(SCAN_B) void scan3_kernel(
    const int* __restrict__ counts, int* __restrict__ incl,
    const int* __restrict__ bsum, int* __restrict__ cur) {
  const int i = blockIdx.x * SCAN_B + threadIdx.x;
  if (i >= SCAN_N) return;
  int v = incl[i] + (blockIdx.x > 0 ? bsum[blockIdx.x - 1] : 0);
  incl[i] = v;
  cur[i] = v - counts[i];  // exclusive start
}

// ---------------------------------------------------------------------------
// CSR build step 2: fill adjacency.
// adj[pos in [0,E)]   = col[e]  (neighbors of row-node, for tau)
// adj[pos in [E,2E)]  = row[e]  (sources of col-node, for aggregation)
// ---------------------------------------------------------------------------
__global__ __launch_bounds__(256) void fill_kernel(const int* __restrict__ row,
                                                   const int* __restrict__ col,
                                                   int* __restrict__ cur,
                                                   int* __restrict__ adj) {
  const int e = blockIdx.x * 256 + threadIdx.x;
  if (e >= N_EDGES) return;
  const int r = row[e];
  const int c = col[e];
  const int pr = atomicAdd(cur + r, 1);
  adj[pr] = c;
  const int pc = atomicAdd(cur + N_NODES + c, 1);
  adj[pc] = r;
}

// ---------------------------------------------------------------------------
// Aggregate (gather form): xnew[n] = relu(sum_{e: col=n} h[row[e]] + b)
// One wave per node; lane holds features [2l, 2l+1].
// ---------------------------------------------------------------------------
__global__ __launch_bounds__(256) void aggregate_kernel(
    const float* __restrict__ h, const int* __restrict__ incl,
    const int* __restrict__ counts, const int* __restrict__ adj,
    const float* __restrict__ b, float* __restrict__ xnew) {
  const int g = blockIdx.x * 256 + threadIdx.x;
  const int n = g >> 6;
  if (n >= N_NODES) return;
  const int lane = g & 63;
  const int cnt = counts[N_NODES + n];
  const int start = incl[N_NODES + n] - cnt;
  const int end = start + cnt;

  float2 a0 = {0.f, 0.f}, a1 = {0.f, 0.f};
  int i = start;
  for (; i + 1 < end; i += 2) {
    const int s0 = adj[i];
    const int s1 = adj[i + 1];
    const float2 v0 = *reinterpret_cast<const float2*>(h + (size_t)s0 * 128 + lane * 2);
    const float2 v1 = *reinterpret_cast<const float2*>(h + (size_t)s1 * 128 + lane * 2);
    a0.x += v0.x; a0.y += v0.y;
    a1.x += v1.x; a1.y += v1.y;
  }
  if (i < end) {
    const int s0 = adj[i];
    const float2 v0 = *reinterpret_cast<const float2*>(h + (size_t)s0 * 128 + lane * 2);
    a0.x += v0.x; a0.y += v0.y;
  }
  const float2 bb = *reinterpret_cast<const float2*>(b + lane * 2);
  float2 o;
  o.x = fmaxf(a0.x + a1.x + bb.x, 0.f);
  o.y = fmaxf(a0.y + a1.y + bb.y, 0.f);
  *reinterpret_cast<float2*>(xnew + (size_t)n * 128 + lane * 2) = o;
}

// ---------------------------------------------------------------------------
// Tau + gated update, fused. One wave per node n:
//   s   = sum_{e: row=n} ||xnew[n] - xnew[col[e]]||^2
//   tau = tanh(s / (deg + 1e-10))
//   x[n] = (1-tau)*x[n] + tau*xnew[n]
// ---------------------------------------------------------------------------
__global__ __launch_bounds__(256) void tau_update_kernel(
    const float* __restrict__ xnew, const int* __restrict__ incl,
    const int* __restrict__ counts, const int* __restrict__ adj,
    float* __restrict__ x) {
  const int g = blockIdx.x * 256 + threadIdx.x;
  const int n = g >> 6;
  if (n >= N_NODES) return;
  const int lane = g & 63;
  const int cnt = counts[n];
  const int start = incl[n] - cnt;
  const int end = start + cnt;

  const float2 mine = *reinterpret_cast<const float2*>(xnew + (size_t)n * 128 + lane * 2);

  float s0 = 0.f, s1 = 0.f;
  int i = start;
  for (; i + 1 < end; i += 2) {
    const int c0 = adj[i];
    const int c1 = adj[i + 1];
    const float2 v0 = *reinterpret_cast<const float2*>(xnew + (size_t)c0 * 128 + lane * 2);
    const float2 v1 = *reinterpret_cast<const float2*>(xnew + (size_t)c1 * 128 + lane * 2);
    const float d0x = mine.x - v0.x, d0y = mine.y - v0.y;
    const float d1x = mine.x - v1.x, d1y = mine.y - v1.y;
    s0 += d0x * d0x + d0y * d0y;
    s1 += d1x * d1x + d1y * d1y;
  }
  if (i < end) {
    const int c0 = adj[i];
    const float2 v0 = *reinterpret_cast<const float2*>(xnew + (size_t)c0 * 128 + lane * 2);
    const float d0x = mine.x - v0.x, d0y = mine.y - v0.y;
    s0 += d0x * d0x + d0y * d0y;
  }
  float s = s0 + s1;
  // full 64-lane reduce
  s += __shfl_xor(s, 1);
  s += __shfl_xor(s, 2);
  s += __shfl_xor(s, 4);
  s += __shfl_xor(s, 8);
  s += __shfl_xor(s, 16);
  s += __shfl_xor(s, 32);
  const float tau = tanhf(s / ((float)cnt + 1e-10f));

  float2 xv = *reinterpret_cast<float2*>(x + (size_t)n * 128 + lane * 2);
  xv.x = (1.f - tau) * xv.x + tau * mine.x;
  xv.y = (1.f - tau) * xv.y + tau * mine.y;
  *reinterpret_cast<float2*>(x + (size_t)n * 128 + lane * 2) = xv;
}

// ---------------------------------------------------------------------------
extern "C" void kernel_launch(void* const* d_in, const int* in_sizes, int n_in,
                              void* d_out, int out_size, void* d_ws,
                              size_t ws_size, hipStream_t stream) {
  const float* x_in = (const float*)d_in[0];
  const int* ei = (const int*)d_in[1];
  const float* W_in = (const float*)d_in[2];
  const float* W_convs = (const float*)d_in[3];
  const float* b_convs = (const float*)d_in[4];
  const float* W_fc = (const float*)d_in[5];
  const float* b_fc = (const float*)d_in[6];
  float* out = (float*)d_out;

  const int* row = ei;
  const int* col = ei + N_EDGES;

  // Workspace layout
  const size_t NF = (size_t)N_NODES * HID;  // 12.8M floats
  float* x_cur = (float*)d_ws;              // 51.2 MB
  float* h = x_cur + NF;                    // 51.2 MB
  float* xnew = h + NF;                     // 51.2 MB
  int* counts = (int*)(xnew + NF);          // 2N ints
  int* incl = counts + SCAN_N;              // 2N ints
  int* cur = incl + SCAN_N;                 // 2N ints
  int* bsum = cur + SCAN_N;                 // 256 ints
  int* adj = bsum + 256;                    // 2E ints = 12.8 MB

  const int GEMM_BLOCKS = N_NODES / 16;            // 6250
  const int EDGE_BLOCKS = (N_EDGES + 255) / 256;   // 6250
  const int WAVE_BLOCKS = (N_NODES * 64 + 255) / 256;  // 25000

  // ---- CSR build (structure only, once per call) ----
  hipMemsetAsync(counts, 0, SCAN_N * sizeof(int), stream);
  count_kernel<<<EDGE_BLOCKS, 256, 0, stream>>>(row, col, counts);
  scan1_kernel<<<SCAN_NB, SCAN_B, 0, stream>>>(counts, incl, bsum);
  scan2_kernel<<<1, 256, 0, stream>>>(bsum);
  scan3_kernel<<<SCAN_NB, SCAN_B, 0, stream>>>(counts, incl, bsum, cur);
  fill_kernel<<<EDGE_BLOCKS, 256, 0, stream>>>(row, col, cur, adj);

  // ---- 1. x = x_in @ W_in ----
  gemm_kernel<2><<<GEMM_BLOCKS, 256, 0, stream>>>(x_in, W_in, nullptr, x_cur);

  for (int l = 0; l < NLAYERS; ++l) {
    const float* Wl = W_convs + (size_t)l * HID * HID;
    const float* bl = b_convs + (size_t)l * HID;

    gemm_kernel<2><<<GEMM_BLOCKS, 256, 0, stream>>>(x_cur, Wl, nullptr, h);
    aggregate_kernel<<<WAVE_BLOCKS, 256, 0, stream>>>(h, incl, counts, adj, bl, xnew);
    tau_update_kernel<<<WAVE_BLOCKS, 256, 0, stream>>>(xnew, incl, counts, adj, x_cur);
  }

  gemm_kernel<1><<<GEMM_BLOCKS, 256, 0, stream>>>(x_cur, W_fc, b_fc, out);
}

// Round 3
// 1200.619 us; speedup vs baseline: 8.0642x; 1.6398x over previous
//
#include <hip/hip_runtime.h>
#include <hip/hip_bf16.h>

// Problem constants (from reference)
#define N_NODES 100000
#define N_EDGES 1600000
#define HID 128
#define OUTC 64
#define NLAYERS 3

#define M_PAD 100032            // 64-row-tile padded M (1563 * 64)
#define SCAN_N (2 * N_NODES)    // joint scan over [row_counts | col_counts]
#define SCAN_B 1024
#define SCAN_NB ((SCAN_N + SCAN_B - 1) / SCAN_B)  // 196

typedef __attribute__((ext_vector_type(8))) short short8;
typedef __attribute__((ext_vector_type(4))) float f32x4;

__device__ __forceinline__ unsigned short f2b(float f) {
  return __builtin_bit_cast(unsigned short, __float2bfloat16(f));
}
__device__ __forceinline__ float blo(unsigned int u) {  // low bf16 -> f32
  return __builtin_bit_cast(float, u << 16);
}
__device__ __forceinline__ float bhi(unsigned int u) {  // high bf16 -> f32
  return __builtin_bit_cast(float, u & 0xffff0000u);
}

// ---------------------------------------------------------------------------
// Cast x_in (f32) -> xb (bf16), zero-filling pad rows [N_NODES, M_PAD).
// ---------------------------------------------------------------------------
__global__ __launch_bounds__(256) void cast_x_kernel(
    const float* __restrict__ x, unsigned short* __restrict__ xb) {
  const int i4 = blockIdx.x * 256 + threadIdx.x;  // float4 index, covers M_PAD*32
  unsigned short o[4] = {0, 0, 0, 0};
  if (i4 < N_NODES * 32) {
    const float4 v = reinterpret_cast<const float4*>(x)[i4];
    o[0] = f2b(v.x); o[1] = f2b(v.y); o[2] = f2b(v.z); o[3] = f2b(v.w);
  }
  *reinterpret_cast<ushort2*>(xb + (size_t)i4 * 4) = make_ushort2(o[0] | ((unsigned)o[1] << 16) ? 0 : 0, 0); // placeholder avoided below
}

// (replaced: simpler scalar-pack version)
__global__ __launch_bounds__(256) void cast_x2_kernel(
    const float* __restrict__ x, unsigned int* __restrict__ xb) {
  const int i2 = blockIdx.x * 256 + threadIdx.x;  // uint index = 2 bf16
  if (i2 >= M_PAD * 64) return;
  unsigned int p = 0;
  if (i2 < N_NODES * 64) {
    const float2 v = reinterpret_cast<const float2*>(x)[i2];
    p = (unsigned)f2b(v.x) | ((unsigned)f2b(v.y) << 16);
  }
  xb[i2] = p;
}

// ---------------------------------------------------------------------------
// Cast + transpose all weights into Wt[n][k] bf16.  All matrices have K=128.
// blocks: [0,128) W_in | [128,512) W_convs | [512,576) W_fc
// ---------------------------------------------------------------------------
__global__ __launch_bounds__(128) void cast_w_kernel(
    const float* __restrict__ W_in, const float* __restrict__ W_convs,
    const float* __restrict__ W_fc, unsigned short* __restrict__ wt) {
  const int b = blockIdx.x;
  const int k = threadIdx.x;
  const float* src;
  unsigned short* dst;
  int n, N;
  if (b < 128) {
    n = b; N = 128; src = W_in; dst = wt + n * 128;
  } else if (b < 512) {
    const int l = (b - 128) >> 7;
    n = (b - 128) & 127; N = 128;
    src = W_convs + (size_t)l * 16384;
    dst = wt + 16384 * (1 + l) + n * 128;
  } else {
    n = b - 512; N = 64; src = W_fc; dst = wt + 65536 + n * 128;
  }
  dst[k] = f2b(src[k * N + n]);
}

// ---------------------------------------------------------------------------
// MFMA GEMM: Y[m][n] = sum_k Xb[m][k] * Wt[n][k]  (K=128, bf16 in, f32 acc)
// Block = 4 waves x 16 rows = 64 rows.  Wave computes 16 x (NT*16) tile.
// MODE 0: write f32 Y + bf16 Yb (N=128, no bias)    [input fc; in-place-safe]
// MODE 1: write bf16 Yb only   (N=128, no bias)     [conv linear]
// MODE 2: write f32 Y + bias, store-guarded (N=64)  [final fc]
// ---------------------------------------------------------------------------
template <int MODE>
__global__ __launch_bounds__(256) void gemm_mfma_kernel(
    const unsigned short* __restrict__ Xb, const unsigned short* __restrict__ Wt,
    const float* __restrict__ bias, float* __restrict__ Y,
    unsigned short* __restrict__ Yb) {
  constexpr int NT = (MODE == 2) ? 4 : 8;  // n-tiles of 16
  const int wave = threadIdx.x >> 6;
  const int lane = threadIdx.x & 63;
  const int row0 = blockIdx.x * 64 + wave * 16;
  const int lm = lane & 15;        // m (A) / n (B) index within tile
  const int lk = (lane >> 4) * 8;  // k-group offset

  f32x4 acc[NT];
#pragma unroll
  for (int t = 0; t < NT; ++t) acc[t] = {0.f, 0.f, 0.f, 0.f};

  const unsigned short* a_base = Xb + (size_t)(row0 + lm) * 128 + lk;
#pragma unroll
  for (int ki = 0; ki < 4; ++ki) {
    const short8 a = *reinterpret_cast<const short8*>(a_base + ki * 32);
#pragma unroll
    for (int t = 0; t < NT; ++t) {
      const short8 b =
          *reinterpret_cast<const short8*>(Wt + (t * 16 + lm) * 128 + ki * 32 + lk);
      acc[t] = __builtin_amdgcn_mfma_f32_16x16x32_bf16(a, b, acc[t], 0, 0, 0);
    }
  }

  const int orow = row0 + (lane >> 4) * 4;  // + r
#pragma unroll
  for (int t = 0; t < NT; ++t) {
#pragma unroll
    for (int r = 0; r < 4; ++r) {
      const int rr = orow + r;
      const int cc = t * 16 + lm;
      const float v = acc[t][r];
      if (MODE == 2) {
        if (rr < N_NODES) Y[(size_t)rr * OUTC + cc] = v + bias[cc];
      } else {
        if (MODE == 0) Y[(size_t)rr * 128 + cc] = v;
        Yb[(size_t)rr * 128 + cc] = f2b(v);
      }
    }
  }
}

// ---------------------------------------------------------------------------
// CSR build (unchanged from round 2)
// ---------------------------------------------------------------------------
__global__ __launch_bounds__(256) void count_kernel(const int* __restrict__ row,
                                                    const int* __restrict__ col,
                                                    int* __restrict__ counts) {
  const int e = blockIdx.x * 256 + threadIdx.x;
  if (e >= N_EDGES) return;
  atomicAdd(counts + row[e], 1);
  atomicAdd(counts + N_NODES + col[e], 1);
}

__global__ __launch_bounds__(SCAN_B) void scan1_kernel(
    const int* __restrict__ counts, int* __restrict__ incl,
    int* __restrict__ bsum) {
  __shared__ int tmp[SCAN_B];
  const int i = blockIdx.x * SCAN_B + threadIdx.x;
  tmp[threadIdx.x] = (i < SCAN_N) ? counts[i] : 0;
  __syncthreads();
  for (int d = 1; d < SCAN_B; d <<= 1) {
    int t = (threadIdx.x >= d) ? tmp[threadIdx.x - d] : 0;
    __syncthreads();
    tmp[threadIdx.x] += t;
    __syncthreads();
  }
  if (i < SCAN_N) incl[i] = tmp[threadIdx.x];
  if (threadIdx.x == SCAN_B - 1) bsum[blockIdx.x] = tmp[SCAN_B - 1];
}

__global__ __launch_bounds__(256) void scan2_kernel(int* __restrict__ bsum) {
  __shared__ int tmp[256];
  tmp[threadIdx.x] = (threadIdx.x < SCAN_NB) ? bsum[threadIdx.x] : 0;
  __syncthreads();
  for (int d = 1; d < 256; d <<= 1) {
    int t = (threadIdx.x >= d) ? tmp[threadIdx.x - d] : 0;
    __syncthreads();
    tmp[threadIdx.x] += t;
    __syncthreads();
  }
  if (threadIdx.x < SCAN_NB) bsum[threadIdx.x] = tmp[threadIdx.x];
}

__global__ __launch_bounds__(SCAN_B) void scan3_kernel(
    const int* __restrict__ counts, int* __restrict__ incl,
    const int* __restrict__ bsum, int* __restrict__ cur) {
  const int i = blockIdx.x * SCAN_B + threadIdx.x;
  if (i >= SCAN_N) return;
  int v = incl[i] + (blockIdx.x > 0 ? bsum[blockIdx.x - 1] : 0);
  incl[i] = v;
  cur[i] = v - counts[i];
}

__global__ __launch_bounds__(256) void fill_kernel(const int* __restrict__ row,
                                                   const int* __restrict__ col,
                                                   int* __restrict__ cur,
                                                   int* __restrict__ adj) {
  const int e = blockIdx.x * 256 + threadIdx.x;
  if (e >= N_EDGES) return;
  const int r = row[e];
  const int c = col[e];
  const int pr = atomicAdd(cur + r, 1);
  adj[pr] = c;
  const int pc = atomicAdd(cur + N_NODES + c, 1);
  adj[pc] = r;
}

// ---------------------------------------------------------------------------
// Aggregate (gather): xnewb[n] = bf16(relu(sum_{e: col=n} hb[row[e]] + b))
// One wave per node; lane holds features [2l, 2l+1] as packed bf16x2.
// ---------------------------------------------------------------------------
__global__ __launch_bounds__(256) void aggregate_kernel(
    const unsigned int* __restrict__ hb, const int* __restrict__ incl,
    const int* __restrict__ counts, const int* __restrict__ adj,
    const float* __restrict__ b, unsigned int* __restrict__ xnewb) {
  const int g = blockIdx.x * 256 + threadIdx.x;
  const int n = g >> 6;
  if (n >= N_NODES) return;
  const int lane = g & 63;
  const int cnt = counts[N_NODES + n];
  const int start = incl[N_NODES + n] - cnt;
  const int end = start + cnt;

  float a0x = 0.f, a0y = 0.f, a1x = 0.f, a1y = 0.f;
  int i = start;
  for (; i + 1 < end; i += 2) {
    const unsigned int v0 = hb[(size_t)adj[i] * 64 + lane];
    const unsigned int v1 = hb[(size_t)adj[i + 1] * 64 + lane];
    a0x += blo(v0); a0y += bhi(v0);
    a1x += blo(v1); a1y += bhi(v1);
  }
  if (i < end) {
    const unsigned int v0 = hb[(size_t)adj[i] * 64 + lane];
    a0x += blo(v0); a0y += bhi(v0);
  }
  const float2 bb = *reinterpret_cast<const float2*>(b + lane * 2);
  const float ox = fmaxf(a0x + a1x + bb.x, 0.f);
  const float oy = fmaxf(a0y + a1y + bb.y, 0.f);
  xnewb[(size_t)n * 64 + lane] = (unsigned)f2b(ox) | ((unsigned)f2b(oy) << 16);
}

// ---------------------------------------------------------------------------
// Tau + gated update, fused.  One wave per node n:
//   s   = sum_{e: row=n} ||xnew[n] - xnew[col[e]]||^2   (bf16 values)
//   tau = tanh(s / (deg + 1e-10))
//   x[n] = (1-tau)*x[n] + tau*xnew[n];  also write xb = bf16(x) for next GEMM
// ---------------------------------------------------------------------------
__global__ __launch_bounds__(256) void tau_update_kernel(
    const unsigned int* __restrict__ xnewb, const int* __restrict__ incl,
    const int* __restrict__ counts, const int* __restrict__ adj,
    float* __restrict__ x, unsigned int* __restrict__ xb) {
  const int g = blockIdx.x * 256 + threadIdx.x;
  const int n = g >> 6;
  if (n >= N_NODES) return;
  const int lane = g & 63;
  const int cnt = counts[n];
  const int start = incl[n] - cnt;
  const int end = start + cnt;

  const unsigned int mp = xnewb[(size_t)n * 64 + lane];
  const float mx = blo(mp), my = bhi(mp);

  float s0 = 0.f, s1 = 0.f;
  int i = start;
  for (; i + 1 < end; i += 2) {
    const unsigned int v0 = xnewb[(size_t)adj[i] * 64 + lane];
    const unsigned int v1 = xnewb[(size_t)adj[i + 1] * 64 + lane];
    const float d0x = mx - blo(v0), d0y = my - bhi(v0);
    const float d1x = mx - blo(v1), d1y = my - bhi(v1);
    s0 += d0x * d0x + d0y * d0y;
    s1 += d1x * d1x + d1y * d1y;
  }
  if (i < end) {
    const unsigned int v0 = xnewb[(size_t)adj[i] * 64 + lane];
    const float d0x = mx - blo(v0), d0y = my - bhi(v0);
    s0 += d0x * d0x + d0y * d0y;
  }
  float s = s0 + s1;
  s += __shfl_xor(s, 1);
  s += __shfl_xor(s, 2);
  s += __shfl_xor(s, 4);
  s += __shfl_xor(s, 8);
  s += __shfl_xor(s, 16);
  s += __shfl_xor(s, 32);
  const float tau = tanhf(s / ((float)cnt + 1e-10f));

  float2 xv = *reinterpret_cast<float2*>(x + (size_t)n * 128 + lane * 2);
  xv.x = (1.f - tau) * xv.x + tau * mx;
  xv.y = (1.f - tau) * xv.y + tau * my;
  *reinterpret_cast<float2*>(x + (size_t)n * 128 + lane * 2) = xv;
  xb[(size_t)n * 64 + lane] = (unsigned)f2b(xv.x) | ((unsigned)f2b(xv.y) << 16);
}

// ---------------------------------------------------------------------------
extern "C" void kernel_launch(void* const* d_in, const int* in_sizes, int n_in,
                              void* d_out, int out_size, void* d_ws,
                              size_t ws_size, hipStream_t stream) {
  const float* x_in = (const float*)d_in[0];
  const int* ei = (const int*)d_in[1];
  const float* W_in = (const float*)d_in[2];
  const float* W_convs = (const float*)d_in[3];
  const float* b_convs = (const float*)d_in[4];
  const float* W_fc = (const float*)d_in[5];
  const float* b_fc = (const float*)d_in[6];
  float* out = (float*)d_out;

  const int* row = ei;
  const int* col = ei + N_EDGES;

  // Workspace layout
  const size_t PF = (size_t)M_PAD * HID;        // 12,804,096
  float* x_cur = (float*)d_ws;                  // PF f32   (51.2 MB)
  unsigned short* xb = (unsigned short*)(x_cur + PF);  // PF bf16 (25.6 MB)
  unsigned short* hb = xb + PF;                 // PF bf16
  unsigned short* xnewb = hb + PF;              // PF bf16
  unsigned short* wt = xnewb + PF;              // 73,728 bf16
  int* counts = (int*)(wt + 73728);             // 2N
  int* incl = counts + SCAN_N;
  int* cur = incl + SCAN_N;
  int* bsum = cur + SCAN_N;                     // 1024
  int* adj = bsum + 1024;                       // 2E
  // total ~143.4 MB

  const int GEMM_BLOCKS = M_PAD / 64;                   // 1563
  const int EDGE_BLOCKS = (N_EDGES + 255) / 256;        // 6250
  const int WAVE_BLOCKS = (N_NODES * 64 + 255) / 256;   // 25000
  const int CASTX_BLOCKS = (M_PAD * 64) / 256;          // 25008

  // ---- casts ----
  cast_x2_kernel<<<CASTX_BLOCKS, 256, 0, stream>>>(x_in, (unsigned int*)xb);
  cast_w_kernel<<<576, 128, 0, stream>>>(W_in, W_convs, W_fc, wt);

  // ---- CSR build (structure only) ----
  hipMemsetAsync(counts, 0, SCAN_N * sizeof(int), stream);
  count_kernel<<<EDGE_BLOCKS, 256, 0, stream>>>(row, col, counts);
  scan1_kernel<<<SCAN_NB, SCAN_B, 0, stream>>>(counts, incl, bsum);
  scan2_kernel<<<1, 256, 0, stream>>>(bsum);
  scan3_kernel<<<SCAN_NB, SCAN_B, 0, stream>>>(counts, incl, bsum, cur);
  fill_kernel<<<EDGE_BLOCKS, 256, 0, stream>>>(row, col, cur, adj);

  // ---- input fc: x = x_in @ W_in  (in-place xb -> xb is safe: rows are
  //      read only by the wave that writes them, reads precede writes) ----
  gemm_mfma_kernel<0><<<GEMM_BLOCKS, 256, 0, stream>>>(xb, wt, nullptr, x_cur, xb);

  for (int l = 0; l < NLAYERS; ++l) {
    const unsigned short* wtl = wt + 16384 * (1 + l);
    const float* bl = b_convs + (size_t)l * HID;

    gemm_mfma_kernel<1><<<GEMM_BLOCKS, 256, 0, stream>>>(xb, wtl, nullptr, nullptr, hb);
    aggregate_kernel<<<WAVE_BLOCKS, 256, 0, stream>>>(
        (const unsigned int*)hb, incl, counts, adj, bl, (unsigned int*)xnewb);
    tau_update_kernel<<<WAVE_BLOCKS, 256, 0, stream>>>(
        (const unsigned int*)xnewb, incl, counts, adj, x_cur, (unsigned int*)xb);
  }

  gemm_mfma_kernel<2><<<GEMM_BLOCKS, 256, 0, stream>>>(xb, wt + 65536, b_fc, out, nullptr);
}

// Round 4
// 833.990 us; speedup vs baseline: 11.6092x; 1.4396x over previous
//
#include <hip/hip_runtime.h>
#include <hip/hip_bf16.h>

// Problem constants (from reference)
#define N_NODES 100000
#define N_EDGES 1600000
#define HID 128
#define OUTC 64
#define NLAYERS 3

#define M_PAD 100032            // 64-row-tile padded M (1563 * 64)
#define SCAN_N (2 * N_NODES)    // joint scan over [row_counts | col_counts]
#define SCAN_B 1024
#define SCAN_NB ((SCAN_N + SCAN_B - 1) / SCAN_B)  // 196

typedef __attribute__((ext_vector_type(8))) short short8;
typedef __attribute__((ext_vector_type(4))) float f32x4;

__device__ __forceinline__ unsigned short f2b(float f) {
  return __builtin_bit_cast(unsigned short, __float2bfloat16(f));
}
__device__ __forceinline__ float blo(unsigned int u) {  // low bf16 -> f32
  return __builtin_bit_cast(float, u << 16);
}
__device__ __forceinline__ float bhi(unsigned int u) {  // high bf16 -> f32
  return __builtin_bit_cast(float, u & 0xffff0000u);
}

// ---------------------------------------------------------------------------
// Cast x_in (f32) -> xb (bf16 packed), zero-filling pad rows.
// ---------------------------------------------------------------------------
__global__ __launch_bounds__(256) void cast_x2_kernel(
    const float* __restrict__ x, unsigned int* __restrict__ xb) {
  const int i2 = blockIdx.x * 256 + threadIdx.x;  // uint index = 2 bf16
  if (i2 >= M_PAD * 64) return;
  unsigned int p = 0;
  if (i2 < N_NODES * 64) {
    const float2 v = reinterpret_cast<const float2*>(x)[i2];
    p = (unsigned)f2b(v.x) | ((unsigned)f2b(v.y) << 16);
  }
  xb[i2] = p;
}

// ---------------------------------------------------------------------------
// Cast + transpose all weights into Wt[n][k] bf16.  All matrices have K=128.
// blocks: [0,128) W_in | [128,512) W_convs | [512,576) W_fc
// ---------------------------------------------------------------------------
__global__ __launch_bounds__(128) void cast_w_kernel(
    const float* __restrict__ W_in, const float* __restrict__ W_convs,
    const float* __restrict__ W_fc, unsigned short* __restrict__ wt) {
  const int b = blockIdx.x;
  const int k = threadIdx.x;
  const float* src;
  unsigned short* dst;
  int n, N;
  if (b < 128) {
    n = b; N = 128; src = W_in; dst = wt + n * 128;
  } else if (b < 512) {
    const int l = (b - 128) >> 7;
    n = (b - 128) & 127; N = 128;
    src = W_convs + (size_t)l * 16384;
    dst = wt + 16384 * (1 + l) + n * 128;
  } else {
    n = b - 512; N = 64; src = W_fc; dst = wt + 65536 + n * 128;
  }
  dst[k] = f2b(src[k * N + n]);
}

// ---------------------------------------------------------------------------
// MFMA GEMM: Y[m][n] = sum_k Xb[m][k] * Wt[n][k]  (K=128, bf16 in, f32 acc)
// Block = 4 waves x 16 rows = 64 rows.  Wave computes 16 x (NT*16) tile.
// MODE 1: write bf16 Yb only   (N=128, no bias)     [fc_in / conv linear]
// MODE 2: write f32 Y + bias, store-guarded (N=64)  [final fc]
// ---------------------------------------------------------------------------
template <int MODE>
__global__ __launch_bounds__(256) void gemm_mfma_kernel(
    const unsigned short* __restrict__ Xb, const unsigned short* __restrict__ Wt,
    const float* __restrict__ bias, float* __restrict__ Y,
    unsigned short* __restrict__ Yb) {
  constexpr int NT = (MODE == 2) ? 4 : 8;  // n-tiles of 16
  const int wave = threadIdx.x >> 6;
  const int lane = threadIdx.x & 63;
  const int row0 = blockIdx.x * 64 + wave * 16;
  const int lm = lane & 15;        // m (A) / n (B) index within tile
  const int lk = (lane >> 4) * 8;  // k-group offset

  f32x4 acc[NT];
#pragma unroll
  for (int t = 0; t < NT; ++t) acc[t] = {0.f, 0.f, 0.f, 0.f};

  const unsigned short* a_base = Xb + (size_t)(row0 + lm) * 128 + lk;
#pragma unroll
  for (int ki = 0; ki < 4; ++ki) {
    const short8 a = *reinterpret_cast<const short8*>(a_base + ki * 32);
#pragma unroll
    for (int t = 0; t < NT; ++t) {
      const short8 b =
          *reinterpret_cast<const short8*>(Wt + (t * 16 + lm) * 128 + ki * 32 + lk);
      acc[t] = __builtin_amdgcn_mfma_f32_16x16x32_bf16(a, b, acc[t], 0, 0, 0);
    }
  }

  const int orow = row0 + (lane >> 4) * 4;  // + r
#pragma unroll
  for (int t = 0; t < NT; ++t) {
#pragma unroll
    for (int r = 0; r < 4; ++r) {
      const int rr = orow + r;
      const int cc = t * 16 + lm;
      const float v = acc[t][r];
      if (MODE == 2) {
        if (rr < N_NODES) Y[(size_t)rr * OUTC + cc] = v + bias[cc];
      } else {
        Yb[(size_t)rr * 128 + cc] = f2b(v);
      }
    }
  }
}

// ---------------------------------------------------------------------------
// CSR build step 1: per-node degree counts + per-edge ranks.
// counts[0..N)  = out-degree (row)  |  counts[N..2N) = in-degree (col)
// ranks[e] = (rank within row segment) | (rank within col segment)<<16
// ---------------------------------------------------------------------------
__global__ __launch_bounds__(256) void count_kernel(
    const int* __restrict__ row, const int* __restrict__ col,
    int* __restrict__ counts, unsigned int* __restrict__ ranks) {
  const int e = blockIdx.x * 256 + threadIdx.x;
  if (e >= N_EDGES) return;
  const int pr = atomicAdd(counts + row[e], 1);
  const int pc = atomicAdd(counts + N_NODES + col[e], 1);
  ranks[e] = (unsigned)pr | ((unsigned)pc << 16);
}

__global__ __launch_bounds__(SCAN_B) void scan1_kernel(
    const int* __restrict__ counts, int* __restrict__ incl,
    int* __restrict__ bsum) {
  __shared__ int tmp[SCAN_B];
  const int i = blockIdx.x * SCAN_B + threadIdx.x;
  tmp[threadIdx.x] = (i < SCAN_N) ? counts[i] : 0;
  __syncthreads();
  for (int d = 1; d < SCAN_B; d <<= 1) {
    int t = (threadIdx.x >= d) ? tmp[threadIdx.x - d] : 0;
    __syncthreads();
    tmp[threadIdx.x] += t;
    __syncthreads();
  }
  if (i < SCAN_N) incl[i] = tmp[threadIdx.x];
  if (threadIdx.x == SCAN_B - 1) bsum[blockIdx.x] = tmp[SCAN_B - 1];
}

__global__ __launch_bounds__(256) void scan2_kernel(int* __restrict__ bsum) {
  __shared__ int tmp[256];
  tmp[threadIdx.x] = (threadIdx.x < SCAN_NB) ? bsum[threadIdx.x] : 0;
  __syncthreads();
  for (int d = 1; d < 256; d <<= 1) {
    int t = (threadIdx.x >= d) ? tmp[threadIdx.x - d] : 0;
    __syncthreads();
    tmp[threadIdx.x] += t;
    __syncthreads();
  }
  if (threadIdx.x < SCAN_NB) bsum[threadIdx.x] = tmp[threadIdx.x];
}

// Scan step C: finalize inclusive scan; cur[i] = exclusive start.
__global__ __launch_bounds__(SCAN_B) void scan3_kernel(
    const int* __restrict__ counts, int* __restrict__ incl,
    const int* __restrict__ bsum, int* __restrict__ cur) {
  const int i = blockIdx.x * SCAN_B + threadIdx.x;
  if (i >= SCAN_N) return;
  int v = incl[i] + (blockIdx.x > 0 ? bsum[blockIdx.x - 1] : 0);
  incl[i] = v;
  cur[i] = v - counts[i];
}

// ---------------------------------------------------------------------------
// CSR build step 2: fill adjacency — atomic-free (positions from ranks).
// adj[pos in [0,E)]   = col[e]  (neighbors of row-node, for tau)
// adj[pos in [E,2E)]  = row[e]  (sources of col-node, for aggregation)
// ---------------------------------------------------------------------------
__global__ __launch_bounds__(256) void fill_kernel(
    const int* __restrict__ row, const int* __restrict__ col,
    const unsigned int* __restrict__ ranks, const int* __restrict__ cur,
    int* __restrict__ adj) {
  const int e = blockIdx.x * 256 + threadIdx.x;
  if (e >= N_EDGES) return;
  const int r = row[e];
  const int c = col[e];
  const unsigned int u = ranks[e];
  adj[cur[r] + (int)(u & 0xffffu)] = c;
  adj[cur[N_NODES + c] + (int)(u >> 16)] = r;
}

// ---------------------------------------------------------------------------
// Aggregate (gather): xnewb[n] = bf16(relu(sum_{e: col=n} hb[row[e]] + b))
// One wave per node; lane holds features [2l, 2l+1] packed bf16x2. Unroll 4.
// ---------------------------------------------------------------------------
__global__ __launch_bounds__(256) void aggregate_kernel(
    const unsigned int* __restrict__ hb, const int* __restrict__ incl,
    const int* __restrict__ counts, const int* __restrict__ adj,
    const float* __restrict__ b, unsigned int* __restrict__ xnewb) {
  const int g = blockIdx.x * 256 + threadIdx.x;
  const int n = g >> 6;
  if (n >= N_NODES) return;
  const int lane = g & 63;
  const int cnt = counts[N_NODES + n];
  const int start = incl[N_NODES + n] - cnt;
  const int end = start + cnt;

  float a0x = 0.f, a0y = 0.f, a1x = 0.f, a1y = 0.f;
  float a2x = 0.f, a2y = 0.f, a3x = 0.f, a3y = 0.f;
  int i = start;
  for (; i + 3 < end; i += 4) {
    const unsigned int v0 = hb[(size_t)adj[i] * 64 + lane];
    const unsigned int v1 = hb[(size_t)adj[i + 1] * 64 + lane];
    const unsigned int v2 = hb[(size_t)adj[i + 2] * 64 + lane];
    const unsigned int v3 = hb[(size_t)adj[i + 3] * 64 + lane];
    a0x += blo(v0); a0y += bhi(v0);
    a1x += blo(v1); a1y += bhi(v1);
    a2x += blo(v2); a2y += bhi(v2);
    a3x += blo(v3); a3y += bhi(v3);
  }
  for (; i < end; ++i) {
    const unsigned int v0 = hb[(size_t)adj[i] * 64 + lane];
    a0x += blo(v0); a0y += bhi(v0);
  }
  const float2 bb = *reinterpret_cast<const float2*>(b + lane * 2);
  const float ox = fmaxf(((a0x + a1x) + (a2x + a3x)) + bb.x, 0.f);
  const float oy = fmaxf(((a0y + a1y) + (a2y + a3y)) + bb.y, 0.f);
  xnewb[(size_t)n * 64 + lane] = (unsigned)f2b(ox) | ((unsigned)f2b(oy) << 16);
}

// ---------------------------------------------------------------------------
// Tau + gated update, fused (x kept in bf16).  One wave per node n:
//   s   = sum_{e: row=n} ||xnew[n] - xnew[col[e]]||^2
//   tau = tanh(s / (deg + 1e-10))
//   x[n] = (1-tau)*x[n] + tau*xnew[n]   (read+write bf16 x)
// ---------------------------------------------------------------------------
__global__ __launch_bounds__(256) void tau_update_kernel(
    const unsigned int* __restrict__ xnewb, const int* __restrict__ incl,
    const int* __restrict__ counts, const int* __restrict__ adj,
    unsigned int* __restrict__ x) {
  const int g = blockIdx.x * 256 + threadIdx.x;
  const int n = g >> 6;
  if (n >= N_NODES) return;
  const int lane = g & 63;
  const int cnt = counts[n];
  const int start = incl[n] - cnt;
  const int end = start + cnt;

  const unsigned int mp = xnewb[(size_t)n * 64 + lane];
  const float mx = blo(mp), my = bhi(mp);

  float s0 = 0.f, s1 = 0.f, s2 = 0.f, s3 = 0.f;
  int i = start;
  for (; i + 3 < end; i += 4) {
    const unsigned int v0 = xnewb[(size_t)adj[i] * 64 + lane];
    const unsigned int v1 = xnewb[(size_t)adj[i + 1] * 64 + lane];
    const unsigned int v2 = xnewb[(size_t)adj[i + 2] * 64 + lane];
    const unsigned int v3 = xnewb[(size_t)adj[i + 3] * 64 + lane];
    const float d0x = mx - blo(v0), d0y = my - bhi(v0);
    const float d1x = mx - blo(v1), d1y = my - bhi(v1);
    const float d2x = mx - blo(v2), d2y = my - bhi(v2);
    const float d3x = mx - blo(v3), d3y = my - bhi(v3);
    s0 += d0x * d0x + d0y * d0y;
    s1 += d1x * d1x + d1y * d1y;
    s2 += d2x * d2x + d2y * d2y;
    s3 += d3x * d3x + d3y * d3y;
  }
  for (; i < end; ++i) {
    const unsigned int v0 = xnewb[(size_t)adj[i] * 64 + lane];
    const float d0x = mx - blo(v0), d0y = my - bhi(v0);
    s0 += d0x * d0x + d0y * d0y;
  }
  float s = (s0 + s1) + (s2 + s3);
  s += __shfl_xor(s, 1);
  s += __shfl_xor(s, 2);
  s += __shfl_xor(s, 4);
  s += __shfl_xor(s, 8);
  s += __shfl_xor(s, 16);
  s += __shfl_xor(s, 32);
  const float tau = tanhf(s / ((float)cnt + 1e-10f));

  const unsigned int xp = x[(size_t)n * 64 + lane];
  const float nx = (1.f - tau) * blo(xp) + tau * mx;
  const float ny = (1.f - tau) * bhi(xp) + tau * my;
  x[(size_t)n * 64 + lane] = (unsigned)f2b(nx) | ((unsigned)f2b(ny) << 16);
}

// ---------------------------------------------------------------------------
extern "C" void kernel_launch(void* const* d_in, const int* in_sizes, int n_in,
                              void* d_out, int out_size, void* d_ws,
                              size_t ws_size, hipStream_t stream) {
  const float* x_in = (const float*)d_in[0];
  const int* ei = (const int*)d_in[1];
  const float* W_in = (const float*)d_in[2];
  const float* W_convs = (const float*)d_in[3];
  const float* b_convs = (const float*)d_in[4];
  const float* W_fc = (const float*)d_in[5];
  const float* b_fc = (const float*)d_in[6];
  float* out = (float*)d_out;

  const int* row = ei;
  const int* col = ei + N_EDGES;

  // Workspace layout
  const size_t PF = (size_t)M_PAD * HID;          // 12,804,096 elements
  unsigned short* xb = (unsigned short*)d_ws;     // PF bf16 (cast of x_in)
  unsigned short* xb2 = xb + PF;                  // PF bf16 (current x)
  unsigned short* hb = xb2 + PF;                  // PF bf16
  unsigned short* xnewb = hb + PF;                // PF bf16
  unsigned short* wt = xnewb + PF;                // 73,728 bf16
  int* counts = (int*)(wt + 73728);               // 2N
  int* incl = counts + SCAN_N;                    // 2N
  int* cur = incl + SCAN_N;                       // 2N
  int* bsum = cur + SCAN_N;                       // 1024
  unsigned int* ranks = (unsigned int*)(bsum + 1024);  // E
  int* adj = (int*)(ranks + N_EDGES);             // 2E
  // total ~ 124 MB

  const int GEMM_BLOCKS = M_PAD / 64;                   // 1563
  const int EDGE_BLOCKS = (N_EDGES + 255) / 256;        // 6250
  const int WAVE_BLOCKS = (N_NODES * 64 + 255) / 256;   // 25000
  const int CASTX_BLOCKS = (M_PAD * 64) / 256;          // 25008

  // ---- casts ----
  cast_x2_kernel<<<CASTX_BLOCKS, 256, 0, stream>>>(x_in, (unsigned int*)xb);
  cast_w_kernel<<<576, 128, 0, stream>>>(W_in, W_convs, W_fc, wt);

  // ---- CSR build (structure only) ----
  hipMemsetAsync(counts, 0, SCAN_N * sizeof(int), stream);
  count_kernel<<<EDGE_BLOCKS, 256, 0, stream>>>(row, col, counts, ranks);
  scan1_kernel<<<SCAN_NB, SCAN_B, 0, stream>>>(counts, incl, bsum);
  scan2_kernel<<<1, 256, 0, stream>>>(bsum);
  scan3_kernel<<<SCAN_NB, SCAN_B, 0, stream>>>(counts, incl, bsum, cur);
  fill_kernel<<<EDGE_BLOCKS, 256, 0, stream>>>(row, col, ranks, cur, adj);

  // ---- input fc: xb2 = bf16(xb @ W_in) ----
  gemm_mfma_kernel<1><<<GEMM_BLOCKS, 256, 0, stream>>>(xb, wt, nullptr, nullptr, xb2);

  for (int l = 0; l < NLAYERS; ++l) {
    const unsigned short* wtl = wt + 16384 * (1 + l);
    const float* bl = b_convs + (size_t)l * HID;

    gemm_mfma_kernel<1><<<GEMM_BLOCKS, 256, 0, stream>>>(xb2, wtl, nullptr, nullptr, hb);
    aggregate_kernel<<<WAVE_BLOCKS, 256, 0, stream>>>(
        (const unsigned int*)hb, incl, counts, adj, bl, (unsigned int*)xnewb);
    tau_update_kernel<<<WAVE_BLOCKS, 256, 0, stream>>>(
        (const unsigned int*)xnewb, incl, counts, adj, (unsigned int*)xb2);
  }

  gemm_mfma_kernel<2><<<GEMM_BLOCKS, 256, 0, stream>>>(xb2, wt + 65536, b_fc, out, nullptr);
}